// Round 1
// baseline (1787.429 us; speedup 1.0000x reference)
//
#include <hip/hip_runtime.h>
#include <math.h>

typedef __bf16 bf16x8 __attribute__((ext_vector_type(8)));
typedef float  f32x4  __attribute__((ext_vector_type(4)));

__device__ __forceinline__ unsigned short f2bf(float f) {
    union { float f; unsigned int u; } v; v.f = f;
    unsigned int u = v.u;
    unsigned int r = (u + 0x7FFFu + ((u >> 16) & 1u)) >> 16;  // RNE
    return (unsigned short)r;
}

__device__ __forceinline__ void load_lds16(const void* g, void* l) {
    __builtin_amdgcn_global_load_lds(
        (const __attribute__((address_space(1))) void*)g,
        (__attribute__((address_space(3))) void*)l, 16, 0, 0);
}

__device__ __forceinline__ f32x4 mfma16(bf16x8 a, bf16x8 b, f32x4 c) {
    return __builtin_amdgcn_mfma_f32_16x16x32_bf16(a, b, c, 0, 0, 0);
}

// ---------------- cast fp32 -> bf16 ----------------
__global__ void cast_kernel(const float4* __restrict__ src, ushort4* __restrict__ dst, int n4) {
    int i = blockIdx.x * blockDim.x + threadIdx.x;
    if (i < n4) {
        float4 v = src[i];
        ushort4 o;
        o.x = f2bf(v.x); o.y = f2bf(v.y); o.z = f2bf(v.z); o.w = f2bf(v.w);
        dst[i] = o;
    }
}

// ---------------- GEMM C[m,n] = sum_k A[m,k]*B[n,k], M=N=K=4096 ----------------
// MODE 0: fp32 out only.  MODE 1: rotary -> bf16 out (Q).
// MODE 2: rotary -> bf16 out + fp32 out (K + cache_k).
// MODE 3: fp32 out (cache_v) + transposed bf16 vbT[b,h,d,s].
template <int MODE>
__global__ __launch_bounds__(256, 2) void gemm_bt(
    const unsigned short* __restrict__ A,
    const unsigned short* __restrict__ B,
    float* __restrict__ C32,
    unsigned short* __restrict__ Cb,
    const float* __restrict__ rcos,
    const float* __restrict__ rsin)
{
    constexpr int K = 4096, N = 4096;
    __shared__ unsigned short At[4096];  // 128 rows x 32 k, 16B slots XOR-swizzled
    __shared__ unsigned short Bt[4096];

    const int tid  = threadIdx.x;
    const int lane = tid & 63;
    const int quad = lane >> 4;
    const int l15  = lane & 15;
    const int wv   = tid >> 6;
    const int wm   = (wv >> 1) * 64;
    const int wn   = (wv & 1) * 64;
    const int bm   = blockIdx.x >> 5;
    const int bn   = blockIdx.x & 31;

    f32x4 acc[4][4];
#pragma unroll
    for (int i = 0; i < 4; i++)
#pragma unroll
        for (int j = 0; j < 4; j++) acc[i][j] = (f32x4){0.f, 0.f, 0.f, 0.f};

    const long Abase = (long)bm * 128 * K;
    const long Bbase = (long)bn * 128 * K;

    for (int k0 = 0; k0 < K; k0 += 32) {
        __syncthreads();
#pragma unroll
        for (int c = 0; c < 2; c++) {
            int slot = c * 256 + tid;
            int row  = slot >> 2;
            int kg   = (slot & 3) ^ (row & 3);
            long off = (long)row * K + k0 + kg * 8;
            load_lds16(A + Abase + off, &At[slot * 8]);
            load_lds16(B + Bbase + off, &Bt[slot * 8]);
        }
        __syncthreads();
        bf16x8 af[4], bfr[4];
#pragma unroll
        for (int mi = 0; mi < 4; mi++) {
            int row  = wm + mi * 16 + l15;
            int slot = row * 4 + (quad ^ (row & 3));
            af[mi] = *(const bf16x8*)&At[slot * 8];
        }
#pragma unroll
        for (int ni = 0; ni < 4; ni++) {
            int row  = wn + ni * 16 + l15;
            int slot = row * 4 + (quad ^ (row & 3));
            bfr[ni] = *(const bf16x8*)&Bt[slot * 8];
        }
        __builtin_amdgcn_s_setprio(1);
#pragma unroll
        for (int mi = 0; mi < 4; mi++)
#pragma unroll
            for (int ni = 0; ni < 4; ni++)
                acc[mi][ni] = mfma16(af[mi], bfr[ni], acc[mi][ni]);
        __builtin_amdgcn_s_setprio(0);
    }

    // epilogue: C/D layout col = lane&15, row = quad*4 + reg (m89/m91 verified)
#pragma unroll
    for (int mi = 0; mi < 4; mi++) {
#pragma unroll
        for (int ni = 0; ni < 4; ni++) {
            const int mbase = bm * 128 + wm + mi * 16 + quad * 4;
            const int n     = bn * 128 + wn + ni * 16 + l15;
            if constexpr (MODE == 0) {
#pragma unroll
                for (int r = 0; r < 4; r++)
                    C32[(long)(mbase + r) * N + n] = acc[mi][ni][r];
            } else if constexpr (MODE == 1 || MODE == 2) {
                const int  j  = (n & 127) >> 1;
                const bool ev = (lane & 1) == 0;
#pragma unroll
                for (int r = 0; r < 4; r++) {
                    float v  = acc[mi][ni][r];
                    float vp = __shfl_xor(v, 1, 64);
                    int   m  = mbase + r;
                    int   s  = m & 2047;
                    float c  = rcos[s * 64 + j];
                    float sn = rsin[s * 64 + j];
                    float o  = ev ? (v * c - vp * sn) : (v * c + vp * sn);
                    Cb[(long)m * N + n] = f2bf(o);
                    if constexpr (MODE == 2) C32[(long)m * N + n] = o;
                }
            } else {  // MODE 3: V
#pragma unroll
                for (int r = 0; r < 4; r++)
                    C32[(long)(mbase + r) * N + n] = acc[mi][ni][r];
                ushort4 pk;
                pk.x = f2bf(acc[mi][ni][0]); pk.y = f2bf(acc[mi][ni][1]);
                pk.z = f2bf(acc[mi][ni][2]); pk.w = f2bf(acc[mi][ni][3]);
                const int bb = mbase >> 11, s0 = mbase & 2047;
                const int hh = n >> 7, dd = n & 127;
                *(ushort4*)&Cb[((long)((bb * 32 + hh) * 128 + dd)) * 2048 + s0] = pk;
            }
        }
    }
}

// ---------------- flash attention (causal) ----------------
// Q,K bf16 [b,s,h,d]; VT bf16 [b,h,d,s]; out bf16 [b,s,h,d]
// Changes vs prev round:
//  - heavy-first schedule: qi = 15 - (blockIdx>>6) so the 32-tile diagonal
//    blocks launch at t=0 (kills the low-occupancy tail).
//  - Pt aliases Kt (disjoint lifetimes; one extra barrier between QK^T and
//    P-write). LDS 51200 -> 32768 => 4 blocks/CU (VGPR-limited) instead of 3.
//  - s_setprio(1) around MFMA clusters (T5).
__global__ __launch_bounds__(256, 4) void flash_attn(
    const unsigned short* __restrict__ Qb,
    const unsigned short* __restrict__ Kb,
    const unsigned short* __restrict__ VT,
    unsigned short* __restrict__ Ob)
{
    __shared__ unsigned short Kt[8192];      // 64 keys x 128 d, swizzled 16B slots; P reuses this
    __shared__ unsigned short Vt[8192];      // 128 d x 64 keys, swizzled
    unsigned short* Pt = Kt;                 // alias: P [128 rows][8 slots][8], XOR-swizzled

    const int tid  = threadIdx.x;
    const int lane = tid & 63;
    const int quad = lane >> 4;
    const int l15  = lane & 15;
    const int wv   = tid >> 6;
    const int qi   = 15 - (blockIdx.x >> 6);   // heavy blocks first
    const int bh   = blockIdx.x & 63;
    const int b    = bh >> 5, h = bh & 31;
    const int q0   = qi * 128;
    const float scale = 0.08838834764831845f;

    bf16x8 qf[2][4];
#pragma unroll
    for (int mi = 0; mi < 2; mi++)
#pragma unroll
        for (int ks = 0; ks < 4; ks++) {
            int qrow = q0 + wv * 32 + mi * 16 + l15;
            qf[mi][ks] = *(const bf16x8*)&Qb[(long)(b * 2048 + qrow) * 4096 + h * 128 + ks * 32 + quad * 8];
        }

    f32x4 oacc[2][8];
#pragma unroll
    for (int mi = 0; mi < 2; mi++)
#pragma unroll
        for (int nd = 0; nd < 8; nd++) oacc[mi][nd] = (f32x4){0.f, 0.f, 0.f, 0.f};
    float mrow[2][4], lrow[2][4];
#pragma unroll
    for (int mi = 0; mi < 2; mi++)
#pragma unroll
        for (int r = 0; r < 4; r++) { mrow[mi][r] = -1e30f; lrow[mi][r] = 0.f; }

    const long kbase = (long)b * 2048 * 4096 + h * 128;
    const long vbase = (long)((b * 32 + h) * 128) * 2048;
    const int  nkt   = (qi + 1) * 2;

    for (int kt = 0; kt < nkt; kt++) {
        const int k0 = kt * 64;
        __syncthreads();
#pragma unroll
        for (int c = 0; c < 4; c++) {  // K tile: 1024 slots
            int slot = c * 256 + tid;
            int key  = slot >> 4;
            int dg   = (slot & 15) ^ (key & 15);
            load_lds16(Kb + kbase + (long)(k0 + key) * 4096 + dg * 8, &Kt[slot * 8]);
        }
#pragma unroll
        for (int c = 0; c < 4; c++) {  // VT tile: 1024 slots
            int slot = c * 256 + tid;
            int d    = slot >> 3;
            int kg   = (slot & 7) ^ (d & 7);
            load_lds16(VT + vbase + (long)d * 2048 + k0 + kg * 8, &Vt[slot * 8]);
        }
        __syncthreads();

        // S = Q K^T
        f32x4 sacc[2][4];
#pragma unroll
        for (int mi = 0; mi < 2; mi++)
#pragma unroll
            for (int nk = 0; nk < 4; nk++) sacc[mi][nk] = (f32x4){0.f, 0.f, 0.f, 0.f};
        __builtin_amdgcn_s_setprio(1);
#pragma unroll
        for (int ks = 0; ks < 4; ks++)
#pragma unroll
            for (int nk = 0; nk < 4; nk++) {
                int krow = nk * 16 + l15;
                int slot = krow * 16 + ((ks * 4 + quad) ^ (krow & 15));
                bf16x8 kf = *(const bf16x8*)&Kt[slot * 8];
#pragma unroll
                for (int mi = 0; mi < 2; mi++)
                    sacc[mi][nk] = mfma16(qf[mi][ks], kf, sacc[mi][nk]);
            }
        __builtin_amdgcn_s_setprio(0);

        // scale + causal mask
#pragma unroll
        for (int mi = 0; mi < 2; mi++)
#pragma unroll
            for (int nk = 0; nk < 4; nk++) {
                int key = k0 + nk * 16 + l15;
#pragma unroll
                for (int r = 0; r < 4; r++) {
                    int row = q0 + wv * 32 + mi * 16 + quad * 4 + r;
                    float s = sacc[mi][nk][r] * scale;
                    sacc[mi][nk][r] = (key > row) ? -1e9f : s;
                }
            }

        // online softmax
#pragma unroll
        for (int mi = 0; mi < 2; mi++)
#pragma unroll
            for (int r = 0; r < 4; r++) {
                float tm = fmaxf(fmaxf(sacc[mi][0][r], sacc[mi][1][r]),
                                 fmaxf(sacc[mi][2][r], sacc[mi][3][r]));
                tm = fmaxf(tm, __shfl_xor(tm, 1, 64));
                tm = fmaxf(tm, __shfl_xor(tm, 2, 64));
                tm = fmaxf(tm, __shfl_xor(tm, 4, 64));
                tm = fmaxf(tm, __shfl_xor(tm, 8, 64));
                float mo = mrow[mi][r];
                float mn = fmaxf(mo, tm);
                float a  = __expf(mo - mn);
                mrow[mi][r] = mn;
                float rs = 0.f;
#pragma unroll
                for (int nk = 0; nk < 4; nk++) {
                    float p = __expf(sacc[mi][nk][r] - mn);
                    sacc[mi][nk][r] = p;
                    rs += p;
                }
                rs += __shfl_xor(rs, 1, 64);
                rs += __shfl_xor(rs, 2, 64);
                rs += __shfl_xor(rs, 4, 64);
                rs += __shfl_xor(rs, 8, 64);
                lrow[mi][r] = lrow[mi][r] * a + rs;
#pragma unroll
                for (int nd = 0; nd < 8; nd++) oacc[mi][nd][r] *= a;
            }

        // all waves must be done reading Kt (QK^T) before P overwrites it
        __syncthreads();

        // P: C-layout -> LDS over Kt, XOR-swizzled 16B slots
#pragma unroll
        for (int mi = 0; mi < 2; mi++)
#pragma unroll
            for (int nk = 0; nk < 4; nk++)
#pragma unroll
                for (int r = 0; r < 4; r++) {
                    int row  = wv * 32 + mi * 16 + quad * 4 + r;
                    int col  = nk * 16 + l15;
                    int slot = row * 8 + ((col >> 3) ^ (row & 7));
                    Pt[slot * 8 + (col & 7)] = f2bf(sacc[mi][nk][r]);
                }
        __syncthreads();

        bf16x8 pf[2][2];
#pragma unroll
        for (int mi = 0; mi < 2; mi++)
#pragma unroll
            for (int ks2 = 0; ks2 < 2; ks2++) {
                int row  = wv * 32 + mi * 16 + l15;
                int slot = row * 8 + ((ks2 * 4 + quad) ^ (row & 7));
                pf[mi][ks2] = *(const bf16x8*)&Pt[slot * 8];
            }

        // O += P V
        __builtin_amdgcn_s_setprio(1);
#pragma unroll
        for (int ks2 = 0; ks2 < 2; ks2++)
#pragma unroll
            for (int nd = 0; nd < 8; nd++) {
                int drow = nd * 16 + l15;
                int slot = drow * 8 + ((ks2 * 4 + quad) ^ (drow & 7));
                bf16x8 vf = *(const bf16x8*)&Vt[slot * 8];
#pragma unroll
                for (int mi = 0; mi < 2; mi++)
                    oacc[mi][nd] = mfma16(pf[mi][ks2], vf, oacc[mi][nd]);
            }
        __builtin_amdgcn_s_setprio(0);
    }

    // epilogue: O / l -> bf16 [b,s,h,d]
#pragma unroll
    for (int mi = 0; mi < 2; mi++)
#pragma unroll
        for (int nd = 0; nd < 8; nd++)
#pragma unroll
            for (int r = 0; r < 4; r++) {
                int qrow = q0 + wv * 32 + mi * 16 + quad * 4 + r;
                float o = oacc[mi][nd][r] / lrow[mi][r];
                Ob[(long)(b * 2048 + qrow) * 4096 + h * 128 + nd * 16 + l15] = f2bf(o);
            }
}

extern "C" void kernel_launch(void* const* d_in, const int* in_sizes, int n_in,
                              void* d_out, int out_size, void* d_ws, size_t ws_size,
                              hipStream_t stream) {
    const float* x    = (const float*)d_in[0];
    const float* fcos = (const float*)d_in[1];
    const float* fsin = (const float*)d_in[2];
    const float* wq   = (const float*)d_in[7];
    const float* wk   = (const float*)d_in[8];
    const float* wv   = (const float*)d_in[9];
    const float* wo   = (const float*)d_in[10];

    float* out     = (float*)d_out;
    float* cache_k = out + 16777216;
    float* cache_v = out + 33554432;

    char* ws = (char*)d_ws;
    const size_t SZ = 33554432;  // 16.7M bf16 elements
    unsigned short* xb    = (unsigned short*)(ws + 0 * SZ);
    unsigned short* wqb   = (unsigned short*)(ws + 1 * SZ);
    unsigned short* wkb   = (unsigned short*)(ws + 2 * SZ);
    unsigned short* wvb   = (unsigned short*)(ws + 3 * SZ);
    unsigned short* wob   = (unsigned short*)(ws + 4 * SZ);
    unsigned short* qb    = (unsigned short*)(ws + 5 * SZ);
    unsigned short* kb    = (unsigned short*)(ws + 6 * SZ);
    unsigned short* vbT   = (unsigned short*)(ws + 7 * SZ);
    unsigned short* attnb = (unsigned short*)(ws + 8 * SZ);

    const int n4 = 16777216 / 4;
    dim3 cblk(256), cgrd(n4 / 256);
    cast_kernel<<<cgrd, cblk, 0, stream>>>((const float4*)x,  (ushort4*)xb,  n4);
    cast_kernel<<<cgrd, cblk, 0, stream>>>((const float4*)wq, (ushort4*)wqb, n4);
    cast_kernel<<<cgrd, cblk, 0, stream>>>((const float4*)wk, (ushort4*)wkb, n4);
    cast_kernel<<<cgrd, cblk, 0, stream>>>((const float4*)wv, (ushort4*)wvb, n4);
    cast_kernel<<<cgrd, cblk, 0, stream>>>((const float4*)wo, (ushort4*)wob, n4);

    dim3 ggrd(1024), gblk(256);
    gemm_bt<1><<<ggrd, gblk, 0, stream>>>(xb, wqb, (float*)nullptr, qb, fcos, fsin);
    gemm_bt<2><<<ggrd, gblk, 0, stream>>>(xb, wkb, cache_k, kb, fcos, fsin);
    gemm_bt<3><<<ggrd, gblk, 0, stream>>>(xb, wvb, cache_v, vbT, fcos, fsin);

    flash_attn<<<ggrd, gblk, 0, stream>>>(qb, kb, vbT, attnb);

    gemm_bt<0><<<ggrd, gblk, 0, stream>>>(attnb, wob, out, (unsigned short*)nullptr, fcos, fsin);
}

// Round 3
// 1261.173 us; speedup vs baseline: 1.4173x; 1.4173x over previous
//
#include <hip/hip_runtime.h>
#include <math.h>

typedef __bf16 bf16x8 __attribute__((ext_vector_type(8)));
typedef float  f32x4  __attribute__((ext_vector_type(4)));

__device__ __forceinline__ unsigned short f2bf(float f) {
    union { float f; unsigned int u; } v; v.f = f;
    unsigned int u = v.u;
    unsigned int r = (u + 0x7FFFu + ((u >> 16) & 1u)) >> 16;  // RNE
    return (unsigned short)r;
}

__device__ __forceinline__ void load_lds16(const void* g, void* l) {
    __builtin_amdgcn_global_load_lds(
        (const __attribute__((address_space(1))) void*)g,
        (__attribute__((address_space(3))) void*)l, 16, 0, 0);
}

__device__ __forceinline__ f32x4 mfma16(bf16x8 a, bf16x8 b, f32x4 c) {
    return __builtin_amdgcn_mfma_f32_16x16x32_bf16(a, b, c, 0, 0, 0);
}

// ---------------- cast fp32 -> bf16 ----------------
__global__ void cast_kernel(const float4* __restrict__ src, ushort4* __restrict__ dst, int n4) {
    int i = blockIdx.x * blockDim.x + threadIdx.x;
    if (i < n4) {
        float4 v = src[i];
        ushort4 o;
        o.x = f2bf(v.x); o.y = f2bf(v.y); o.z = f2bf(v.z); o.w = f2bf(v.w);
        dst[i] = o;
    }
}

// ---------------- GEMM C[m,n] = sum_k A[m,k]*B[n,k], M=N=K=4096 ----------------
// MODE 0: fp32 out only.  MODE 1: rotary -> bf16 out (Q).
// MODE 2: rotary -> bf16 out + fp32 out (K + cache_k).
// MODE 3: fp32 out (cache_v) + transposed bf16 vbT[b,h,d,s].
template <int MODE>
__global__ __launch_bounds__(256, 2) void gemm_bt(
    const unsigned short* __restrict__ A,
    const unsigned short* __restrict__ B,
    float* __restrict__ C32,
    unsigned short* __restrict__ Cb,
    const float* __restrict__ rcos,
    const float* __restrict__ rsin)
{
    constexpr int K = 4096, N = 4096;
    __shared__ unsigned short At[4096];  // 128 rows x 32 k, 16B slots XOR-swizzled
    __shared__ unsigned short Bt[4096];

    const int tid  = threadIdx.x;
    const int lane = tid & 63;
    const int quad = lane >> 4;
    const int l15  = lane & 15;
    const int wv   = tid >> 6;
    const int wm   = (wv >> 1) * 64;
    const int wn   = (wv & 1) * 64;
    const int bm   = blockIdx.x >> 5;
    const int bn   = blockIdx.x & 31;

    f32x4 acc[4][4];
#pragma unroll
    for (int i = 0; i < 4; i++)
#pragma unroll
        for (int j = 0; j < 4; j++) acc[i][j] = (f32x4){0.f, 0.f, 0.f, 0.f};

    const long Abase = (long)bm * 128 * K;
    const long Bbase = (long)bn * 128 * K;

    for (int k0 = 0; k0 < K; k0 += 32) {
        __syncthreads();
#pragma unroll
        for (int c = 0; c < 2; c++) {
            int slot = c * 256 + tid;
            int row  = slot >> 2;
            int kg   = (slot & 3) ^ (row & 3);
            long off = (long)row * K + k0 + kg * 8;
            load_lds16(A + Abase + off, &At[slot * 8]);
            load_lds16(B + Bbase + off, &Bt[slot * 8]);
        }
        __syncthreads();
        bf16x8 af[4], bfr[4];
#pragma unroll
        for (int mi = 0; mi < 4; mi++) {
            int row  = wm + mi * 16 + l15;
            int slot = row * 4 + (quad ^ (row & 3));
            af[mi] = *(const bf16x8*)&At[slot * 8];
        }
#pragma unroll
        for (int ni = 0; ni < 4; ni++) {
            int row  = wn + ni * 16 + l15;
            int slot = row * 4 + (quad ^ (row & 3));
            bfr[ni] = *(const bf16x8*)&Bt[slot * 8];
        }
        __builtin_amdgcn_s_setprio(1);
#pragma unroll
        for (int mi = 0; mi < 4; mi++)
#pragma unroll
            for (int ni = 0; ni < 4; ni++)
                acc[mi][ni] = mfma16(af[mi], bfr[ni], acc[mi][ni]);
        __builtin_amdgcn_s_setprio(0);
    }

    // epilogue: C/D layout col = lane&15, row = quad*4 + reg (m89/m91 verified)
#pragma unroll
    for (int mi = 0; mi < 4; mi++) {
#pragma unroll
        for (int ni = 0; ni < 4; ni++) {
            const int mbase = bm * 128 + wm + mi * 16 + quad * 4;
            const int n     = bn * 128 + wn + ni * 16 + l15;
            if constexpr (MODE == 0) {
#pragma unroll
                for (int r = 0; r < 4; r++)
                    C32[(long)(mbase + r) * N + n] = acc[mi][ni][r];
            } else if constexpr (MODE == 1 || MODE == 2) {
                const int  j  = (n & 127) >> 1;
                const bool ev = (lane & 1) == 0;
#pragma unroll
                for (int r = 0; r < 4; r++) {
                    float v  = acc[mi][ni][r];
                    float vp = __shfl_xor(v, 1, 64);
                    int   m  = mbase + r;
                    int   s  = m & 2047;
                    float c  = rcos[s * 64 + j];
                    float sn = rsin[s * 64 + j];
                    float o  = ev ? (v * c - vp * sn) : (v * c + vp * sn);
                    Cb[(long)m * N + n] = f2bf(o);
                    if constexpr (MODE == 2) C32[(long)m * N + n] = o;
                }
            } else {  // MODE 3: V
#pragma unroll
                for (int r = 0; r < 4; r++)
                    C32[(long)(mbase + r) * N + n] = acc[mi][ni][r];
                ushort4 pk;
                pk.x = f2bf(acc[mi][ni][0]); pk.y = f2bf(acc[mi][ni][1]);
                pk.z = f2bf(acc[mi][ni][2]); pk.w = f2bf(acc[mi][ni][3]);
                const int bb = mbase >> 11, s0 = mbase & 2047;
                const int hh = n >> 7, dd = n & 127;
                *(ushort4*)&Cb[((long)((bb * 32 + hh) * 128 + dd)) * 2048 + s0] = pk;
            }
        }
    }
}

// ---------------- flash attention (causal) ----------------
// Q,K bf16 [b,s,h,d]; VT bf16 [b,h,d,s]; out bf16 [b,s,h,d]
// Round-3 = round-2 resubmitted (round-2 bench was an infra failure, no data).
//  - __launch_bounds__(256,2): round-1's (256,4) capped unified VGPR+AGPR at
//    128/wave; kernel needs ~190 -> massive scratch spill (FETCH 232MB->1.16GB).
//    2 blocks/CU is this kernel's register-feasible occupancy.
//  - heavy-first schedule kept: qi = 15 - (blockIdx>>6), diagonal blocks at t=0.
//  - Pt aliases Kt kept (LDS 32768; harmless at 2 blocks/CU, keeps option open).
__global__ __launch_bounds__(256, 2) void flash_attn(
    const unsigned short* __restrict__ Qb,
    const unsigned short* __restrict__ Kb,
    const unsigned short* __restrict__ VT,
    unsigned short* __restrict__ Ob)
{
    __shared__ unsigned short Kt[8192];      // 64 keys x 128 d, swizzled 16B slots; P reuses this
    __shared__ unsigned short Vt[8192];      // 128 d x 64 keys, swizzled
    unsigned short* Pt = Kt;                 // alias: P [128 rows][8 slots][8], XOR-swizzled

    const int tid  = threadIdx.x;
    const int lane = tid & 63;
    const int quad = lane >> 4;
    const int l15  = lane & 15;
    const int wv   = tid >> 6;
    const int qi   = 15 - (blockIdx.x >> 6);   // heavy blocks first
    const int bh   = blockIdx.x & 63;
    const int b    = bh >> 5, h = bh & 31;
    const int q0   = qi * 128;
    const float scale = 0.08838834764831845f;

    bf16x8 qf[2][4];
#pragma unroll
    for (int mi = 0; mi < 2; mi++)
#pragma unroll
        for (int ks = 0; ks < 4; ks++) {
            int qrow = q0 + wv * 32 + mi * 16 + l15;
            qf[mi][ks] = *(const bf16x8*)&Qb[(long)(b * 2048 + qrow) * 4096 + h * 128 + ks * 32 + quad * 8];
        }

    f32x4 oacc[2][8];
#pragma unroll
    for (int mi = 0; mi < 2; mi++)
#pragma unroll
        for (int nd = 0; nd < 8; nd++) oacc[mi][nd] = (f32x4){0.f, 0.f, 0.f, 0.f};
    float mrow[2][4], lrow[2][4];
#pragma unroll
    for (int mi = 0; mi < 2; mi++)
#pragma unroll
        for (int r = 0; r < 4; r++) { mrow[mi][r] = -1e30f; lrow[mi][r] = 0.f; }

    const long kbase = (long)b * 2048 * 4096 + h * 128;
    const long vbase = (long)((b * 32 + h) * 128) * 2048;
    const int  nkt   = (qi + 1) * 2;

    for (int kt = 0; kt < nkt; kt++) {
        const int k0 = kt * 64;
        __syncthreads();
#pragma unroll
        for (int c = 0; c < 4; c++) {  // K tile: 1024 slots
            int slot = c * 256 + tid;
            int key  = slot >> 4;
            int dg   = (slot & 15) ^ (key & 15);
            load_lds16(Kb + kbase + (long)(k0 + key) * 4096 + dg * 8, &Kt[slot * 8]);
        }
#pragma unroll
        for (int c = 0; c < 4; c++) {  // VT tile: 1024 slots
            int slot = c * 256 + tid;
            int d    = slot >> 3;
            int kg   = (slot & 7) ^ (d & 7);
            load_lds16(VT + vbase + (long)d * 2048 + k0 + kg * 8, &Vt[slot * 8]);
        }
        __syncthreads();

        // S = Q K^T
        f32x4 sacc[2][4];
#pragma unroll
        for (int mi = 0; mi < 2; mi++)
#pragma unroll
            for (int nk = 0; nk < 4; nk++) sacc[mi][nk] = (f32x4){0.f, 0.f, 0.f, 0.f};
        __builtin_amdgcn_s_setprio(1);
#pragma unroll
        for (int ks = 0; ks < 4; ks++)
#pragma unroll
            for (int nk = 0; nk < 4; nk++) {
                int krow = nk * 16 + l15;
                int slot = krow * 16 + ((ks * 4 + quad) ^ (krow & 15));
                bf16x8 kf = *(const bf16x8*)&Kt[slot * 8];
#pragma unroll
                for (int mi = 0; mi < 2; mi++)
                    sacc[mi][nk] = mfma16(qf[mi][ks], kf, sacc[mi][nk]);
            }
        __builtin_amdgcn_s_setprio(0);

        // scale + causal mask
#pragma unroll
        for (int mi = 0; mi < 2; mi++)
#pragma unroll
            for (int nk = 0; nk < 4; nk++) {
                int key = k0 + nk * 16 + l15;
#pragma unroll
                for (int r = 0; r < 4; r++) {
                    int row = q0 + wv * 32 + mi * 16 + quad * 4 + r;
                    float s = sacc[mi][nk][r] * scale;
                    sacc[mi][nk][r] = (key > row) ? -1e9f : s;
                }
            }

        // online softmax
#pragma unroll
        for (int mi = 0; mi < 2; mi++)
#pragma unroll
            for (int r = 0; r < 4; r++) {
                float tm = fmaxf(fmaxf(sacc[mi][0][r], sacc[mi][1][r]),
                                 fmaxf(sacc[mi][2][r], sacc[mi][3][r]));
                tm = fmaxf(tm, __shfl_xor(tm, 1, 64));
                tm = fmaxf(tm, __shfl_xor(tm, 2, 64));
                tm = fmaxf(tm, __shfl_xor(tm, 4, 64));
                tm = fmaxf(tm, __shfl_xor(tm, 8, 64));
                float mo = mrow[mi][r];
                float mn = fmaxf(mo, tm);
                float a  = __expf(mo - mn);
                mrow[mi][r] = mn;
                float rs = 0.f;
#pragma unroll
                for (int nk = 0; nk < 4; nk++) {
                    float p = __expf(sacc[mi][nk][r] - mn);
                    sacc[mi][nk][r] = p;
                    rs += p;
                }
                rs += __shfl_xor(rs, 1, 64);
                rs += __shfl_xor(rs, 2, 64);
                rs += __shfl_xor(rs, 4, 64);
                rs += __shfl_xor(rs, 8, 64);
                lrow[mi][r] = lrow[mi][r] * a + rs;
#pragma unroll
                for (int nd = 0; nd < 8; nd++) oacc[mi][nd][r] *= a;
            }

        // all waves must be done reading Kt (QK^T) before P overwrites it
        __syncthreads();

        // P: C-layout -> LDS over Kt, XOR-swizzled 16B slots
#pragma unroll
        for (int mi = 0; mi < 2; mi++)
#pragma unroll
            for (int nk = 0; nk < 4; nk++)
#pragma unroll
                for (int r = 0; r < 4; r++) {
                    int row  = wv * 32 + mi * 16 + quad * 4 + r;
                    int col  = nk * 16 + l15;
                    int slot = row * 8 + ((col >> 3) ^ (row & 7));
                    Pt[slot * 8 + (col & 7)] = f2bf(sacc[mi][nk][r]);
                }
        __syncthreads();

        bf16x8 pf[2][2];
#pragma unroll
        for (int mi = 0; mi < 2; mi++)
#pragma unroll
            for (int ks2 = 0; ks2 < 2; ks2++) {
                int row  = wv * 32 + mi * 16 + l15;
                int slot = row * 8 + ((ks2 * 4 + quad) ^ (row & 7));
                pf[mi][ks2] = *(const bf16x8*)&Pt[slot * 8];
            }

        // O += P V
        __builtin_amdgcn_s_setprio(1);
#pragma unroll
        for (int ks2 = 0; ks2 < 2; ks2++)
#pragma unroll
            for (int nd = 0; nd < 8; nd++) {
                int drow = nd * 16 + l15;
                int slot = drow * 8 + ((ks2 * 4 + quad) ^ (drow & 7));
                bf16x8 vf = *(const bf16x8*)&Vt[slot * 8];
#pragma unroll
                for (int mi = 0; mi < 2; mi++)
                    oacc[mi][nd] = mfma16(pf[mi][ks2], vf, oacc[mi][nd]);
            }
        __builtin_amdgcn_s_setprio(0);
    }

    // epilogue: O / l -> bf16 [b,s,h,d]
#pragma unroll
    for (int mi = 0; mi < 2; mi++)
#pragma unroll
        for (int nd = 0; nd < 8; nd++)
#pragma unroll
            for (int r = 0; r < 4; r++) {
                int qrow = q0 + wv * 32 + mi * 16 + quad * 4 + r;
                float o = oacc[mi][nd][r] / lrow[mi][r];
                Ob[(long)(b * 2048 + qrow) * 4096 + h * 128 + nd * 16 + l15] = f2bf(o);
            }
}

extern "C" void kernel_launch(void* const* d_in, const int* in_sizes, int n_in,
                              void* d_out, int out_size, void* d_ws, size_t ws_size,
                              hipStream_t stream) {
    const float* x    = (const float*)d_in[0];
    const float* fcos = (const float*)d_in[1];
    const float* fsin = (const float*)d_in[2];
    const float* wq   = (const float*)d_in[7];
    const float* wk   = (const float*)d_in[8];
    const float* wv   = (const float*)d_in[9];
    const float* wo   = (const float*)d_in[10];

    float* out     = (float*)d_out;
    float* cache_k = out + 16777216;
    float* cache_v = out + 33554432;

    char* ws = (char*)d_ws;
    const size_t SZ = 33554432;  // 16.7M bf16 elements
    unsigned short* xb    = (unsigned short*)(ws + 0 * SZ);
    unsigned short* wqb   = (unsigned short*)(ws + 1 * SZ);
    unsigned short* wkb   = (unsigned short*)(ws + 2 * SZ);
    unsigned short* wvb   = (unsigned short*)(ws + 3 * SZ);
    unsigned short* wob   = (unsigned short*)(ws + 4 * SZ);
    unsigned short* qb    = (unsigned short*)(ws + 5 * SZ);
    unsigned short* kb    = (unsigned short*)(ws + 6 * SZ);
    unsigned short* vbT   = (unsigned short*)(ws + 7 * SZ);
    unsigned short* attnb = (unsigned short*)(ws + 8 * SZ);

    const int n4 = 16777216 / 4;
    dim3 cblk(256), cgrd(n4 / 256);
    cast_kernel<<<cgrd, cblk, 0, stream>>>((const float4*)x,  (ushort4*)xb,  n4);
    cast_kernel<<<cgrd, cblk, 0, stream>>>((const float4*)wq, (ushort4*)wqb, n4);
    cast_kernel<<<cgrd, cblk, 0, stream>>>((const float4*)wk, (ushort4*)wkb, n4);
    cast_kernel<<<cgrd, cblk, 0, stream>>>((const float4*)wv, (ushort4*)wvb, n4);
    cast_kernel<<<cgrd, cblk, 0, stream>>>((const float4*)wo, (ushort4*)wob, n4);

    dim3 ggrd(1024), gblk(256);
    gemm_bt<1><<<ggrd, gblk, 0, stream>>>(xb, wqb, (float*)nullptr, qb, fcos, fsin);
    gemm_bt<2><<<ggrd, gblk, 0, stream>>>(xb, wkb, cache_k, kb, fcos, fsin);
    gemm_bt<3><<<ggrd, gblk, 0, stream>>>(xb, wvb, cache_v, vbT, fcos, fsin);

    flash_attn<<<ggrd, gblk, 0, stream>>>(qb, kb, vbT, attnb);

    gemm_bt<0><<<ggrd, gblk, 0, stream>>>(attnb, wob, out, (unsigned short*)nullptr, fcos, fsin);
}